// Round 16
// baseline (49.413 us; speedup 1.0000x reference)
//
#include <hip/hip_runtime.h>
#include <hip/hip_bf16.h>
#include <math.h>

#define Bn 128
#define Tn 512
#define Cn 256
#define Hn 64
#define HP2 72          // padded bf16 LDS stride for attn tiles (144 B)
#define SCL 0.18033688011112042f   // log2(e)/8 : exp2-domain softmax scale

typedef __attribute__((ext_vector_type(8))) short short8v;   // 8 bf16
typedef __attribute__((ext_vector_type(4))) float float4v;   // MFMA C/D

__device__ __forceinline__ ushort f2bf(float f) {
    __hip_bfloat16 h = __float2bfloat16(f);   // RNE
    return *reinterpret_cast<ushort*>(&h);
}

// ---------------------------------------------------------------------------
// Prep: wcT4 = W grouped [nh][kc][96 rows][64 k] bf16, pre-swizzled within
// each 128 B row (k2 ^ ((row&7)<<3) ushort idx) so linear global_load_lds
// lands XOR-swizzled (m173). Row r<64: q(nh0)|k(nh1) h=r; r>=64: v h=nh*32+r-64.
// ---------------------------------------------------------------------------
__global__ __launch_bounds__(256) void prep_w_kernel(
    const float* __restrict__ Wq, const float* __restrict__ Wk,
    const float* __restrict__ Wv, ushort* __restrict__ wcT4)
{
    const int g   = blockIdx.x;          // 0..191 : nh*96 + row
    const int nh  = g / 96;
    const int row = g % 96;
    const int c   = threadIdx.x;         // 0..255 : k
    const int kc  = c >> 6;
    const int k2  = c & 63;
    const float* W;
    int h;
    if (row < 64) { W = nh ? Wk : Wq; h = row; }
    else          { W = Wv; h = nh * 32 + (row - 64); }
    wcT4[(((nh * 4 + kc) * 96) + row) * 64 + (k2 ^ ((row & 7) << 3))] =
        f2bf(W[c * Hn + h]);
}

// ---------------------------------------------------------------------------
// QKV GEMM v11: v10 pipeline at 40 KB LDS -> 4 blocks/CU (16 waves), no
// VGPR cap. 1024 blocks x 256 thr. Block = 128 rows x 96 cols (nh half;
// halves of a row-tile 8 apart in dispatch -> same XCD -> x L2-hot).
// K chunked BK=64: x single-buffered (reg-ping, T14), W double-buffered via
// global_load_lds. 2 barriers/chunk; prefetch issued right after barrier2 so
// it flies across the MFMA phase; 4 blocks/CU fill remaining bubbles.
// Wave (wr=wv>>1, wc=wv&1): 64 rows (4 strips) x 48 cols (3 frags).
// Epilogue: overlay bounce -> all-uint4 stores (q|k 4/thr, v 2/thr).
// ---------------------------------------------------------------------------
__global__ __launch_bounds__(256) void qkv_mfma_kernel(
    const float* __restrict__ x, const ushort* __restrict__ wcT4,
    ushort* __restrict__ q, ushort* __restrict__ k, ushort* __restrict__ vT)
{
    __shared__ char lds[40960];
    // [0,16384)      : xbuf [128 r][64 k] bf16 swz; epilogue q|k bounce [128t][64h]
    // [16384, 40960) : wbuf0/1 (12288 B each); epilogue v bounce @16384 (8 KB)
    const int WOFF = 16384;

    const int tid  = threadIdx.x;
    const int lane = tid & 63;
    const int wv   = tid >> 6;             // 0..3
    const int lr   = lane & 15;
    const int hi   = lane >> 4;
    const int wr   = wv >> 1;              // 0..1 : 64-row group
    const int wc   = wv & 1;               // 0..1 : 48-col group

    const int bid     = blockIdx.x;
    const int nh      = (bid >> 3) & 1;
    const int rowtile = (bid & 7) | ((bid >> 4) << 3);   // 0..511
    const long rows0  = (long)rowtile * 128;

    const char* gw = (const char*)wcT4 + (long)nh * 4 * 12288;
    const float4* x4 = (const float4*)x;

    // ---- prologue: W chunk0 DMA + x chunk0 loads ----
    #pragma unroll
    for (int i = 0; i < 3; ++i) {
        int off = (wv * 3 + i) * 1024;
        __builtin_amdgcn_global_load_lds(
            (const __attribute__((address_space(1))) unsigned int*)(gw + off + (lane << 4)),
            (__attribute__((address_space(3))) unsigned int*)(lds + WOFF + off),
            16, 0, 0);
    }
    float4 xr[8];
    #pragma unroll
    for (int i = 0; i < 8; ++i) {
        int idx = tid + i * 256;
        int r = idx >> 4, f = idx & 15;
        xr[i] = x4[(rows0 + r) * 64 + f];
    }

    float4v acc[4][3];
    #pragma unroll
    for (int s = 0; s < 4; ++s)
        #pragma unroll
        for (int n = 0; n < 3; ++n) acc[s][n] = (float4v){0.f, 0.f, 0.f, 0.f};

    for (int kc = 0; kc < 4; ++kc) {
        const int par = kc & 1;
        __syncthreads();   // xbuf free (prev MFMA done); drains this chunk's W DMA + x loads

        // ---- ds_write x(kc) -> xbuf ----
        #pragma unroll
        for (int i = 0; i < 8; ++i) {
            int idx = tid + i * 256;
            int r = idx >> 4, f = idx & 15;
            union { ushort u[4]; uint2 p; } pk;
            pk.u[0] = f2bf(xr[i].x); pk.u[1] = f2bf(xr[i].y);
            pk.u[2] = f2bf(xr[i].z); pk.u[3] = f2bf(xr[i].w);
            *(uint2*)(lds + r * 128 + ((f * 8) ^ ((r & 7) << 4))) = pk.p;
        }
        __syncthreads();   // x visible to all waves

        // ---- issue next chunk's W DMA + x loads (fly across MFMA) ----
        if (kc < 3) {
            const char* gw2 = gw + (kc + 1) * 12288;
            #pragma unroll
            for (int i = 0; i < 3; ++i) {
                int off = (wv * 3 + i) * 1024;
                __builtin_amdgcn_global_load_lds(
                    (const __attribute__((address_space(1))) unsigned int*)(gw2 + off + (lane << 4)),
                    (__attribute__((address_space(3))) unsigned int*)(lds + WOFF + (1 - par) * 12288 + off),
                    16, 0, 0);
            }
            #pragma unroll
            for (int i = 0; i < 8; ++i) {
                int idx = tid + i * 256;
                int r = idx >> 4, f = idx & 15;
                xr[i] = x4[(rows0 + r) * 64 + (kc + 1) * 16 + f];
            }
        }

        // ---- MFMA on chunk kc ----
        const char* wb = lds + WOFF + par * 12288;
        #pragma unroll
        for (int ks = 0; ks < 2; ++ks) {
            const int kb = ks * 64 + hi * 16;
            short8v a[4];
            #pragma unroll
            for (int s = 0; s < 4; ++s) {
                int r = wr * 64 + s * 16 + lr;
                a[s] = *(const short8v*)(lds + r * 128 + (kb ^ ((r & 7) << 4)));
            }
            #pragma unroll
            for (int n = 0; n < 3; ++n) {
                int wrow = wc * 48 + n * 16 + lr;
                short8v wf = *(const short8v*)(wb + wrow * 128 + (kb ^ ((wrow & 7) << 4)));
                #pragma unroll
                for (int s = 0; s < 4; ++s)
                    acc[s][n] = __builtin_amdgcn_mfma_f32_16x16x32_bf16(a[s], wf, acc[s][n], 0, 0, 0);
            }
        }
    }

    __syncthreads();   // all MFMA done -> overlay buffers as bounce

    // ---- bounce: lane(lr,hi) frag (s,n) holds col = wc*48+n*16+lr,
    //      rows t = wr*64+s*16+hi*4+reg ----
    #pragma unroll
    for (int s = 0; s < 4; ++s) {
        const int tb = wr * 64 + s * 16 + hi * 4;
        #pragma unroll
        for (int n = 0; n < 3; ++n) {
            const int col16 = wc * 48 + n * 16;        // wave-uniform
            if (col16 < 64) {                          // q|k: [t][h] scalar
                int h = col16 + lr;
                #pragma unroll
                for (int reg = 0; reg < 4; ++reg) {
                    int t = tb + reg;
                    *(ushort*)(lds + t * 128 + ((h * 2) ^ ((t & 7) << 4))) =
                        f2bf(acc[s][n][reg]);
                }
            } else {                                   // v: [h][t] ushort4
                int hl = col16 - 64 + lr;              // 0..31
                ushort4 pk;
                pk.x = f2bf(acc[s][n][0]); pk.y = f2bf(acc[s][n][1]);
                pk.z = f2bf(acc[s][n][2]); pk.w = f2bf(acc[s][n][3]);
                *(ushort4*)(lds + WOFF + hl * 256 + ((tb * 2) ^ ((hl & 7) << 4))) = pk;
            }
        }
    }
    __syncthreads();

    // ---- coalesced stores ----
    {
        const int bb = (int)(rows0 >> 9);
        const int t0 = (int)(rows0 & 511);
        ushort* qk = nh ? k : q;
        #pragma unroll
        for (int i = 0; i < 4; ++i) {                  // q|k: 1024 uint4
            int idx = tid + i * 256;
            int t = idx >> 3, f = idx & 7;
            uint4 w = *(const uint4*)(lds + t * 128 + ((f * 16) ^ ((t & 7) << 4)));
            *(uint4*)(qk + (rows0 + t) * Hn + f * 8) = w;
        }
        #pragma unroll
        for (int i = 0; i < 2; ++i) {                  // v: 512 uint4
            int idx = tid + i * 256;
            int hl = idx >> 4, fv = idx & 15;
            uint4 w = *(const uint4*)(lds + WOFF + hl * 256 + ((fv * 16) ^ ((hl & 7) << 4)));
            *(uint4*)(vT + ((long)bb * Hn + nh * 32 + hl) * Tn + t0 + fv * 8) = w;
        }
    }
}

// ---------------------------------------------------------------------------
// MFMA flash attention, 128-row Q tile, 8 waves (512 thr). Unchanged (r13).
// ---------------------------------------------------------------------------
__global__ __launch_bounds__(512) void attn_mfma_kernel(
    const ushort* __restrict__ q, const ushort* __restrict__ k,
    const ushort* __restrict__ vT, float* __restrict__ out)
{
    __shared__ ushort Ks[64 * HP2];        // [key s][h]
    __shared__ ushort Vt[64 * HP2];        // [h][key s]
    __shared__ ushort Pl[8][16 * HP2];     // per-wave P rows

    const int tid = threadIdx.x;
    const int f   = blockIdx.x;            // 0..511
    const int c   = f & 255;
    const int b   = c >> 1;
    const int par = c & 1;
    const int qtp = (f < 256) ? par : (3 - par);   // q-tile 0..3
    const int ntiles = 2 * qtp + 2;

    const long base  = (long)b * Tn * Hn;
    const int lane = tid & 63;
    const int wv   = tid >> 6;             // 0..7
    const int lr   = lane & 15;
    const int hi   = lane >> 4;

    const int qrow_g = qtp * 128 + wv * 16;
    const int mrow0  = qrow_g + hi * 4;

    short8v qa[2];
    {
        const ushort* qp = q + base + (long)(qrow_g + lr) * Hn + hi * 8;
        qa[0] = *(const short8v*)(qp);
        qa[1] = *(const short8v*)(qp + 32);
    }

    const int sr  = tid >> 3;
    const int sc8 = tid & 7;
    uint4 kreg = *(const uint4*)(k + base + (long)sr * Hn + sc8 * 8);
    uint4 vreg = *(const uint4*)(vT + base + (long)sr * Tn + sc8 * 8);

    float4v o[4];
    #pragma unroll
    for (int n = 0; n < 4; ++n) o[n] = (float4v){0.f, 0.f, 0.f, 0.f};
    float m[4], l[4];
    #pragma unroll
    for (int reg = 0; reg < 4; ++reg) { m[reg] = -INFINITY; l[reg] = 0.f; }

    for (int kt = 0; kt < ntiles; ++kt) {
        __syncthreads();
        *(uint4*)&Ks[sr * HP2 + sc8 * 8] = kreg;
        *(uint4*)&Vt[sr * HP2 + sc8 * 8] = vreg;
        __syncthreads();
        if (kt + 1 < ntiles) {
            kreg = *(const uint4*)(k  + base + (long)((kt + 1) * 64 + sr) * Hn + sc8 * 8);
            vreg = *(const uint4*)(vT + base + (long)sr * Tn + (kt + 1) * 64 + sc8 * 8);
        }
        if (kt * 64 > qrow_g + 15) continue;

        float4v s4[4];
        #pragma unroll
        for (int n = 0; n < 4; ++n) s4[n] = (float4v){0.f, 0.f, 0.f, 0.f};
        #pragma unroll
        for (int ks = 0; ks < 2; ++ks) {
            short8v a = qa[ks];
            #pragma unroll
            for (int n = 0; n < 4; ++n) {
                short8v bb = *(const short8v*)&Ks[(n * 16 + lr) * HP2 + ks * 32 + hi * 8];
                s4[n] = __builtin_amdgcn_mfma_f32_16x16x32_bf16(a, bb, s4[n], 0, 0, 0);
            }
        }

        const bool partial = (kt * 64 + 63 > qrow_g);
        if (partial) {
            #pragma unroll
            for (int n = 0; n < 4; ++n) {
                int kcol = kt * 64 + n * 16 + lr;
                #pragma unroll
                for (int reg = 0; reg < 4; ++reg) {
                    float y = s4[n][reg] * SCL;
                    s4[n][reg] = (kcol <= mrow0 + reg) ? y : -INFINITY;
                }
            }
        } else {
            #pragma unroll
            for (int n = 0; n < 4; ++n)
                #pragma unroll
                for (int reg = 0; reg < 4; ++reg) s4[n][reg] *= SCL;
        }

        #pragma unroll
        for (int reg = 0; reg < 4; ++reg) {
            float mx = fmaxf(fmaxf(s4[0][reg], s4[1][reg]),
                             fmaxf(s4[2][reg], s4[3][reg]));
            mx = fmaxf(mx, __shfl_xor(mx, 1));
            mx = fmaxf(mx, __shfl_xor(mx, 2));
            mx = fmaxf(mx, __shfl_xor(mx, 4));
            mx = fmaxf(mx, __shfl_xor(mx, 8));
            float mN = fmaxf(m[reg], mx);
            float sc = exp2f(m[reg] - mN);
            float ps = 0.f;
            #pragma unroll
            for (int n = 0; n < 4; ++n) {
                float p = exp2f(s4[n][reg] - mN);
                s4[n][reg] = p;
                ps += p;
            }
            ps += __shfl_xor(ps, 1);
            ps += __shfl_xor(ps, 2);
            ps += __shfl_xor(ps, 4);
            ps += __shfl_xor(ps, 8);
            l[reg] = l[reg] * sc + ps;
            m[reg] = mN;
            #pragma unroll
            for (int n = 0; n < 4; ++n) o[n][reg] *= sc;
        }

        #pragma unroll
        for (int n = 0; n < 4; ++n)
            #pragma unroll
            for (int reg = 0; reg < 4; ++reg)
                Pl[wv][(hi * 4 + reg) * HP2 + n * 16 + lr] = f2bf(s4[n][reg]);

        #pragma unroll
        for (int ks = 0; ks < 2; ++ks) {
            short8v a = *(const short8v*)&Pl[wv][lr * HP2 + ks * 32 + hi * 8];
            #pragma unroll
            for (int n = 0; n < 4; ++n) {
                short8v bb = *(const short8v*)&Vt[(n * 16 + lr) * HP2 + ks * 32 + hi * 8];
                o[n] = __builtin_amdgcn_mfma_f32_16x16x32_bf16(a, bb, o[n], 0, 0, 0);
            }
        }
    }

    #pragma unroll
    for (int reg = 0; reg < 4; ++reg) {
        float inv = 1.0f / l[reg];
        float* orow = out + base + (long)(mrow0 + reg) * Hn;
        #pragma unroll
        for (int n = 0; n < 4; ++n)
            orow[n * 16 + lr] = o[n][reg] * inv;
    }
}

extern "C" void kernel_launch(void* const* d_in, const int* in_sizes, int n_in,
                              void* d_out, int out_size, void* d_ws, size_t ws_size,
                              hipStream_t stream) {
    const float* x  = (const float*)d_in[0];
    const float* Wq = (const float*)d_in[1];
    const float* Wk = (const float*)d_in[2];
    const float* Wv = (const float*)d_in[3];
    float* out = (float*)d_out;

    const size_t n = (size_t)Bn * Tn * Hn;
    ushort* qws  = (ushort*)d_ws;
    ushort* kws  = qws + n;
    ushort* vTs  = kws + n;
    ushort* wcT4 = vTs + n;      // grouped K-chunked pre-swizzled bf16 W, 96 KB

    prep_w_kernel<<<dim3(192), 256, 0, stream>>>(Wq, Wk, Wv, wcT4);
    qkv_mfma_kernel<<<dim3(1024), 256, 0, stream>>>(x, wcT4, qws, kws, vTs);
    attn_mfma_kernel<<<dim3(512), 512, 0, stream>>>(qws, kws, vTs, out);
}